// Round 3
// baseline (315.683 us; speedup 1.0000x reference)
//
#include <hip/hip_runtime.h>

#define C_ 512
#define T_ 2048
#define N_TOK 16384
#define K_CB 4096

typedef __attribute__((ext_vector_type(4))) float f32x4;
typedef __attribute__((ext_vector_type(8))) short short8;

static __device__ __forceinline__ unsigned short f2bf(float f) {
    unsigned u = __float_as_uint(f);
    unsigned r = (u + 0x7FFFu + ((u >> 16) & 1u)) >> 16;  // RNE
    return (unsigned short)r;
}

typedef const __attribute__((address_space(1))) void* gas_t;
typedef __attribute__((address_space(3))) void* las_t;
static __device__ __forceinline__ void stage16(const void* g, void* l) {
    __builtin_amdgcn_global_load_lds((gas_t)g, (las_t)l, 16, 0, 0);
}

// ---------------- Kernel 1: transpose student (B,C,T)->(N,C) bf16 + per-token stats ----------------
__global__ __launch_bounds__(256) void k1_prep(
    const float* __restrict__ student,   // (B,C,T) fp32
    const int* __restrict__ codes,       // (B,T) int32
    const float* __restrict__ codebook,  // (K,C) fp32
    unsigned short* __restrict__ Abf,    // (N,C) bf16 out
    float* __restrict__ xnorm, float* __restrict__ dtarg,
    float* __restrict__ accum)
{
    __shared__ float tile[64][65];
    __shared__ int lcodes[64];
    __shared__ float wsum[8];
    int tid = threadIdx.x;
    int b = blockIdx.x >> 5;            // 32 t-tiles per batch
    int t0 = (blockIdx.x & 31) << 6;
    int cx = tid & 63;                  // lane
    int q  = tid >> 6;                  // wave
    if (tid < 64) lcodes[tid] = codes[b * T_ + t0 + tid];
    __syncthreads();
    float ax2[16], ad2[16];
#pragma unroll
    for (int p = 0; p < 16; ++p) { ax2[p] = 0.f; ad2[p] = 0.f; }
    for (int c0 = 0; c0 < C_; c0 += 64) {
#pragma unroll
        for (int p = 0; p < 16; ++p) {
            int ch = p * 4 + q;
            tile[ch][cx] = student[(size_t)b * (C_ * T_) + (size_t)(c0 + ch) * T_ + t0 + cx];
        }
        __syncthreads();
#pragma unroll
        for (int p = 0; p < 16; ++p) {
            int ty = p * 4 + q;
            float x = tile[cx][ty];
            int n = b * T_ + t0 + ty;
            Abf[(size_t)n * C_ + c0 + cx] = f2bf(x);
            ax2[p] += x * x;
            float cb = codebook[(size_t)lcodes[ty] * C_ + c0 + cx];
            float d = x - cb;
            ad2[p] += d * d;
        }
        __syncthreads();
    }
    float sq_local = 0.f, td_local = 0.f;
#pragma unroll
    for (int p = 0; p < 16; ++p) {
        float sx = ax2[p], sd = ad2[p];
#pragma unroll
        for (int m = 1; m < 64; m <<= 1) {
            sx += __shfl_xor(sx, m);
            sd += __shfl_xor(sd, m);
        }
        if (cx == 0) {
            int n = b * T_ + t0 + p * 4 + q;
            xnorm[n] = sx;
            float dt = sqrtf(sd);
            dtarg[n] = dt;
            sq_local += sd;
            td_local += dt;
        }
    }
    if (cx == 0) { wsum[q] = sq_local; wsum[4 + q] = td_local; }
    __syncthreads();
    if (tid == 0) {
        atomicAdd(&accum[2], wsum[0] + wsum[1] + wsum[2] + wsum[3]);
        atomicAdd(&accum[3], wsum[4] + wsum[5] + wsum[6] + wsum[7]);
    }
}

// ---------------- Kernel 1b: codebook -> bf16 + row norms + init of reduce buffers ----------------
__global__ __launch_bounds__(256) void k1_cb(
    const float* __restrict__ codebook,
    unsigned short* __restrict__ CBbf,
    float* __restrict__ cbnorm,
    float* __restrict__ s_sum,
    unsigned long long* __restrict__ minpack,
    float* __restrict__ accum)
{
    int tid = threadIdx.x;
    int gidx = blockIdx.x * 256 + tid;
    if (gidx < N_TOK) { s_sum[gidx] = 0.f; minpack[gidx] = ~0ull; }
    if (gidx < 8) accum[gidx] = 0.f;
    int lane = tid & 63;
    int w = tid >> 6;
    int row = blockIdx.x * 4 + w;
    const float* src = codebook + (size_t)row * C_ + lane * 8;
    float4 v0 = *(const float4*)(src);
    float4 v1 = *(const float4*)(src + 4);
    float s = v0.x*v0.x + v0.y*v0.y + v0.z*v0.z + v0.w*v0.w
            + v1.x*v1.x + v1.y*v1.y + v1.z*v1.z + v1.w*v1.w;
    uint4 pk;
    pk.x = (unsigned)f2bf(v0.x) | ((unsigned)f2bf(v0.y) << 16);
    pk.y = (unsigned)f2bf(v0.z) | ((unsigned)f2bf(v0.w) << 16);
    pk.z = (unsigned)f2bf(v1.x) | ((unsigned)f2bf(v1.y) << 16);
    pk.w = (unsigned)f2bf(v1.z) | ((unsigned)f2bf(v1.w) << 16);
    *(uint4*)(CBbf + (size_t)row * C_ + lane * 8) = pk;
#pragma unroll
    for (int m = 1; m < 64; m <<= 1) s += __shfl_xor(s, m);
    if (lane == 0) cbnorm[row] = s;
}

// ---------------- Kernel 2: dbuf + early-issue staging + XOR-swizzled LDS ----------------
// grid = 4096 (128 row-blocks x 32 col-blocks); block = 256 (4 waves = 2x2 of 64x64)
// 2x32KB LDS double-buffer, BK=64, global_load_lds w16 (linear dest, pre-swizzled source),
// one __syncthreads per K-step (vmcnt drain hidden under ds_read+MFMA of current tile)
__global__ __launch_bounds__(256) void k2_main(
    const unsigned short* __restrict__ Abf,
    const unsigned short* __restrict__ CBbf,
    const float* __restrict__ xnorm,
    const float* __restrict__ dtarg,
    const float* __restrict__ cbnorm,
    float* __restrict__ s_sum,
    unsigned long long* __restrict__ minpack)
{
    __shared__ __align__(16) unsigned short aL[2][128 * 64];
    __shared__ __align__(16) unsigned short bL[2][128 * 64];
    int tid = threadIdx.x;
    int lane = tid & 63;
    int w = tid >> 6;
    int wr = w >> 1, wc = w & 1;
    int l15 = lane & 15, hi = lane >> 4;

    // XCD-aware swizzle: 4096 % 8 == 0, each XCD gets a contiguous 512-WG chunk
    int orig = blockIdx.x;
    int swz = (orig & 7) * 512 + (orig >> 3);
    int rb = swz >> 5, cb = swz & 31;
    int row0 = rb * 128, col0 = cb * 128;

    // Staging geometry: thread tid owns LDS chunk (i*256 + tid)*16B -> linear (row, col):
    //   row = i*32 + (tid>>3), col = (tid&7)*8  (bf16 elems, 64-elem rows)
    // T2 swizzle phys[row][col] = logical[row][col ^ ((row&7)*8)] realized by
    // pre-swizzling the GLOBAL source column (rule 21: linear dest + swz source + swz read).
    int srow = tid >> 3;
    int scol = ((tid & 7) * 8) ^ ((srow & 7) * 8);
    const unsigned short* gA = Abf + (size_t)(row0 + srow) * C_ + scol;
    const unsigned short* gB = CBbf + (size_t)(col0 + srow) * C_ + scol;

    f32x4 acc[4][4];
#pragma unroll
    for (int rt = 0; rt < 4; ++rt)
#pragma unroll
        for (int ct = 0; ct < 4; ++ct)
            acc[rt][ct] = (f32x4){0.f, 0.f, 0.f, 0.f};

#define STAGE(buf, kof)                                                       \
    _Pragma("unroll")                                                         \
    for (int i = 0; i < 4; ++i) {                                             \
        stage16(gA + (size_t)i * (32 * C_) + (kof), &aL[buf][w * 512 + i * 2048]); \
        stage16(gB + (size_t)i * (32 * C_) + (kof), &bL[buf][w * 512 + i * 2048]); \
    }

    // prologue: stage tile 0 into buf 0
    STAGE(0, 0)
    __syncthreads();                     // drains vmcnt(0): tile 0 ready

    int axor = (l15 & 7) * 8;            // read-side swizzle (row&7 == l15&7 here)
    int cur = 0;
#pragma unroll
    for (int t = 0; t < 8; ++t) {
        if (t < 7) { STAGE(cur ^ 1, (t + 1) * 64) }   // issue next tile EARLY
#pragma unroll
        for (int ks = 0; ks < 2; ++ks) {
            short8 af[4], bfr[4];
#pragma unroll
            for (int rt = 0; rt < 4; ++rt)
                af[rt] = *(const short8*)(&aL[cur][(wr * 64 + rt * 16 + l15) * 64 + (((ks * 32 + hi * 8)) ^ axor)]);
#pragma unroll
            for (int ct = 0; ct < 4; ++ct)
                bfr[ct] = *(const short8*)(&bL[cur][(wc * 64 + ct * 16 + l15) * 64 + (((ks * 32 + hi * 8)) ^ axor)]);
#pragma unroll
            for (int rt = 0; rt < 4; ++rt)
#pragma unroll
                for (int ct = 0; ct < 4; ++ct)
                    acc[rt][ct] = __builtin_amdgcn_mfma_f32_16x16x32_bf16(af[rt], bfr[ct], acc[rt][ct], 0, 0, 0);
        }
        if (t < 7) {
            __syncthreads();             // vmcnt(0) drain (hidden by the compute above) + barrier
            cur ^= 1;
        }
    }
#undef STAGE

    // epilogue: dot -> distance -> exp-sum + argmin over this WG's 128 cols
    float cbn[4];
#pragma unroll
    for (int ct = 0; ct < 4; ++ct)
        cbn[ct] = cbnorm[col0 + wc * 64 + ct * 16 + l15];
#pragma unroll
    for (int rt = 0; rt < 4; ++rt) {
#pragma unroll
        for (int r = 0; r < 4; ++r) {
            int row = row0 + wr * 64 + rt * 16 + hi * 4 + r;
            float xn = xnorm[row];
            float dt = dtarg[row];
            float sv = 0.f, dm = 3.4e38f;
            unsigned ix = 0u;
#pragma unroll
            for (int ct = 0; ct < 4; ++ct) {
                float dot = acc[rt][ct][r];
                float d2 = fmaxf(xn + cbn[ct] - 2.f * dot, 0.f);
                float d = sqrtf(d2);
                sv += __expf(fminf(dt - d, 80.f));
                unsigned col = (unsigned)(col0 + wc * 64 + ct * 16 + l15);
                if (d < dm) { dm = d; ix = col; }
            }
            // reduce across the 16 lanes (l15) sharing this row
#pragma unroll
            for (int m = 1; m < 16; m <<= 1) {
                sv += __shfl_xor(sv, m);
                float od = __shfl_xor(dm, m);
                unsigned oi = __shfl_xor(ix, m);
                if (od < dm || (od == dm && oi < ix)) { dm = od; ix = oi; }
            }
            if (l15 == 0) {
                atomicAdd(&s_sum[row], sv);
                unsigned long long pk = ((unsigned long long)__float_as_uint(dm) << 32) | (unsigned long long)ix;
                atomicMin(&minpack[row], pk);
            }
        }
    }
}

// ---------------- Kernel 3a: per-token CE/accuracy reduce ----------------
__global__ __launch_bounds__(256) void k3a(
    const float* __restrict__ s_sum,
    const unsigned long long* __restrict__ minpack,
    const int* __restrict__ codes,
    float* __restrict__ accum)
{
    __shared__ float wce[4], wac[4];
    int tid = threadIdx.x;
    int n = blockIdx.x * 256 + tid;
    float ce = logf(s_sum[n]);
    unsigned pred = (unsigned)(minpack[n] & 0xFFFFFFFFull);
    float ok = (pred == (unsigned)codes[n]) ? 1.f : 0.f;
#pragma unroll
    for (int m = 1; m < 64; m <<= 1) {
        ce += __shfl_xor(ce, m);
        ok += __shfl_xor(ok, m);
    }
    int lane = tid & 63, w = tid >> 6;
    if (lane == 0) { wce[w] = ce; wac[w] = ok; }
    __syncthreads();
    if (tid == 0) {
        atomicAdd(&accum[0], wce[0] + wce[1] + wce[2] + wce[3]);
        atomicAdd(&accum[1], wac[0] + wac[1] + wac[2] + wac[3]);
    }
}

// ---------------- Kernel 3b: finalize 5 outputs ----------------
__global__ void k3b(const float* __restrict__ accum, float* __restrict__ out)
{
    if (threadIdx.x == 0 && blockIdx.x == 0) {
        float ce   = accum[0] / (float)N_TOK;
        float accy = accum[1] / (float)N_TOK;
        float emb  = accum[2] / ((float)N_TOK * (float)C_);
        float td   = accum[3] / (float)N_TOK;
        out[0] = emb + ce;   // total_loss (EMB_W=CE_W=1)
        out[1] = emb;        // emb_to_codebook_loss
        out[2] = ce;         // ce_loss
        out[3] = accy;       // token_accuracy
        out[4] = td;         // emb_to_target_dist
    }
}

extern "C" void kernel_launch(void* const* d_in, const int* in_sizes, int n_in,
                              void* d_out, int out_size, void* d_ws, size_t ws_size,
                              hipStream_t stream)
{
    const float* student  = (const float*)d_in[0];
    const int*   codes    = (const int*)d_in[1];
    const float* codebook = (const float*)d_in[2];
    // d_in[3] distance_matrix is unused by the reference.
    float* out = (float*)d_out;

    char* ws = (char*)d_ws;
    unsigned short* Abf   = (unsigned short*)(ws);                 // 16 MiB
    unsigned short* CBbf  = (unsigned short*)(ws + 16777216);      // 4 MiB
    float* xnorm          = (float*)(ws + 20971520);               // 64 KiB
    float* dtarg          = (float*)(ws + 21037056);               // 64 KiB
    float* cbnorm         = (float*)(ws + 21102592);               // 16 KiB
    float* s_sum          = (float*)(ws + 21118976);               // 64 KiB
    unsigned long long* minpack = (unsigned long long*)(ws + 21184512); // 128 KiB
    float* accum          = (float*)(ws + 21315584);               // 64 B

    // k1_cb also zero-inits s_sum/minpack/accum (must precede k1_prep's accum atomics)
    hipLaunchKernelGGL(k1_cb, dim3(1024), dim3(256), 0, stream,
                       codebook, CBbf, cbnorm, s_sum, minpack, accum);
    hipLaunchKernelGGL(k1_prep, dim3(256), dim3(256), 0, stream,
                       student, codes, codebook, Abf, xnorm, dtarg, accum);
    hipLaunchKernelGGL(k2_main, dim3(4096), dim3(256), 0, stream,
                       Abf, CBbf, xnorm, dtarg, cbnorm, s_sum, minpack);
    hipLaunchKernelGGL(k3a, dim3(64), dim3(256), 0, stream,
                       s_sum, minpack, codes, accum);
    hipLaunchKernelGGL(k3b, dim3(1), dim3(64), 0, stream, accum, out);
}

// Round 4
// 220.606 us; speedup vs baseline: 1.4310x; 1.4310x over previous
//
#include <hip/hip_runtime.h>

#define C_ 512
#define T_ 2048
#define N_TOK 16384
#define K_CB 4096

typedef __attribute__((ext_vector_type(4))) float f32x4;
typedef __attribute__((ext_vector_type(8))) short short8;

static __device__ __forceinline__ unsigned short f2bf(float f) {
    unsigned u = __float_as_uint(f);
    unsigned r = (u + 0x7FFFu + ((u >> 16) & 1u)) >> 16;  // RNE
    return (unsigned short)r;
}

typedef const __attribute__((address_space(1))) void* gas_t;
typedef __attribute__((address_space(3))) void* las_t;
static __device__ __forceinline__ void stage16(const void* g, void* l) {
    __builtin_amdgcn_global_load_lds((gas_t)g, (las_t)l, 16, 0, 0);
}

// ---------------- Kernel 1: transpose student (B,C,T)->(N,C) bf16 + per-token partial stats ------
// grid = 512: 256 token-tiles x 2 C-halves. Partial sums go to xnorm/dtg2 via atomicAdd
// (zero-initialized by k1_cb). sqrt deferred to consumers (k2 epilogue, k3a).
__global__ __launch_bounds__(256) void k1_prep(
    const float* __restrict__ student,   // (B,C,T) fp32
    const int* __restrict__ codes,       // (B,T) int32
    const float* __restrict__ codebook,  // (K,C) fp32
    unsigned short* __restrict__ Abf,    // (N,C) bf16 out
    float* __restrict__ xnorm, float* __restrict__ dtg2)
{
    __shared__ float tile[64][65];
    __shared__ int lcodes[64];
    int tid = threadIdx.x;
    int tnum  = blockIdx.x >> 1;
    int chalf = blockIdx.x & 1;
    int b  = tnum >> 5;
    int t0 = (tnum & 31) << 6;
    int cbase = chalf << 8;             // 0 or 256
    int cx = tid & 63;                  // lane
    int q  = tid >> 6;                  // wave
    if (tid < 64) lcodes[tid] = codes[b * T_ + t0 + tid];
    __syncthreads();
    float ax2[16], ad2[16];
#pragma unroll
    for (int p = 0; p < 16; ++p) { ax2[p] = 0.f; ad2[p] = 0.f; }
    for (int c0 = cbase; c0 < cbase + 256; c0 += 64) {
#pragma unroll
        for (int p = 0; p < 16; ++p) {
            int ch = p * 4 + q;
            tile[ch][cx] = student[(size_t)b * (C_ * T_) + (size_t)(c0 + ch) * T_ + t0 + cx];
        }
        __syncthreads();
#pragma unroll
        for (int p = 0; p < 16; ++p) {
            int ty = p * 4 + q;
            float x = tile[cx][ty];
            int n = b * T_ + t0 + ty;
            Abf[(size_t)n * C_ + c0 + cx] = f2bf(x);
            ax2[p] += x * x;
            float cb = codebook[(size_t)lcodes[ty] * C_ + c0 + cx];
            float d = x - cb;
            ad2[p] += d * d;
        }
        __syncthreads();
    }
#pragma unroll
    for (int p = 0; p < 16; ++p) {
        float sx = ax2[p], sd = ad2[p];
#pragma unroll
        for (int m = 1; m < 64; m <<= 1) {
            sx += __shfl_xor(sx, m);
            sd += __shfl_xor(sd, m);
        }
        if (cx == 0) {
            int n = b * T_ + t0 + p * 4 + q;
            atomicAdd(&xnorm[n], sx);
            atomicAdd(&dtg2[n], sd);
        }
    }
}

// ---------------- Kernel 1b: codebook -> bf16 + row norms + init of all reduce buffers -----------
__global__ __launch_bounds__(256) void k1_cb(
    const float* __restrict__ codebook,
    unsigned short* __restrict__ CBbf,
    float* __restrict__ cbnorm,
    float* __restrict__ s_sum,
    unsigned long long* __restrict__ minpack,
    float* __restrict__ xnorm, float* __restrict__ dtg2,
    float* __restrict__ accum)
{
    int tid = threadIdx.x;
    int gidx = blockIdx.x * 256 + tid;
    if (gidx < N_TOK) {
        s_sum[gidx] = 0.f; minpack[gidx] = ~0ull;
        xnorm[gidx] = 0.f; dtg2[gidx] = 0.f;
    }
    if (gidx < 8) accum[gidx] = 0.f;
    int lane = tid & 63;
    int w = tid >> 6;
    int row = blockIdx.x * 4 + w;
    const float* src = codebook + (size_t)row * C_ + lane * 8;
    float4 v0 = *(const float4*)(src);
    float4 v1 = *(const float4*)(src + 4);
    float s = v0.x*v0.x + v0.y*v0.y + v0.z*v0.z + v0.w*v0.w
            + v1.x*v1.x + v1.y*v1.y + v1.z*v1.z + v1.w*v1.w;
    uint4 pk;
    pk.x = (unsigned)f2bf(v0.x) | ((unsigned)f2bf(v0.y) << 16);
    pk.y = (unsigned)f2bf(v0.z) | ((unsigned)f2bf(v0.w) << 16);
    pk.z = (unsigned)f2bf(v1.x) | ((unsigned)f2bf(v1.y) << 16);
    pk.w = (unsigned)f2bf(v1.z) | ((unsigned)f2bf(v1.w) << 16);
    *(uint4*)(CBbf + (size_t)row * C_ + lane * 8) = pk;
#pragma unroll
    for (int m = 1; m < 64; m <<= 1) s += __shfl_xor(s, m);
    if (lane == 0) cbnorm[row] = s;
}

// ---------------- Kernel 2: 256x256 tile, BK=32, 4-slot LDS ring, counted vmcnt (T3/T4/T5) ------
// grid = 1024 (64 rb x 16 cb); block = 512 (8 waves = 2x4, each owns 128x64 of C)
// Ring: 3 K-tiles always in flight; s_waitcnt vmcnt(8) per step (never 0 until tail).
// Two barriers per K-tile => stage of tile t+3 (slot (t+3)&3 = (t-1)&3) is 2 barriers past
// all reads of tile t-1 -> no clobber race.
__global__ __launch_bounds__(512, 2) void k2_main(
    const unsigned short* __restrict__ Abf,
    const unsigned short* __restrict__ CBbf,
    const float* __restrict__ xnorm,
    const float* __restrict__ dtg2,
    const float* __restrict__ cbnorm,
    float* __restrict__ s_sum,
    unsigned long long* __restrict__ minpack)
{
    __shared__ __align__(16) unsigned short aL[4][256 * 32];   // 4 x 16KB
    __shared__ __align__(16) unsigned short bL[4][256 * 32];   // 4 x 16KB
    int tid = threadIdx.x;
    int lane = tid & 63;
    int w = tid >> 6;                   // 0..7
    int wr = w >> 2, wc = w & 3;        // 2 x 4 wave grid
    int l15 = lane & 15, hi = lane >> 4;

    // XCD-aware swizzle: 1024 % 8 == 0 -> contiguous 128-WG chunk per XCD
    int orig = blockIdx.x;
    int swz = (orig & 7) * 128 + (orig >> 3);
    int rb = swz >> 4, cb = swz & 15;
    int row0 = rb * 256, col0 = cb * 256;

    // Staging: per tile per thread: 2 A chunks + 2 B chunks (16B each).
    // chunk i: LDS elems [i*4096 + tid*8) -> row i*128 + (tid>>2), kslot tid&3 (8 elems).
    // T2 swizzle: source column pre-XORed so LDS[row][s] holds global k-chunk s^(row&3).
    int srow = tid >> 2;
    int scol = (((tid & 3) ^ (srow & 3)) * 8);
    const unsigned short* gA = Abf + (size_t)(row0 + srow) * C_ + scol;
    const unsigned short* gB = CBbf + (size_t)(col0 + srow) * C_ + scol;

#define STAGE(bi, kof) do {                                                  \
        stage16(gA + (kof),                   &aL[bi][tid * 8]);             \
        stage16(gA + 128 * (size_t)C_ + (kof), &aL[bi][4096 + tid * 8]);     \
        stage16(gB + (kof),                   &bL[bi][tid * 8]);             \
        stage16(gB + 128 * (size_t)C_ + (kof), &bL[bi][4096 + tid * 8]);     \
    } while (0)

    f32x4 acc[8][4];
#pragma unroll
    for (int rt = 0; rt < 8; ++rt)
#pragma unroll
        for (int ct = 0; ct < 4; ++ct)
            acc[rt][ct] = (f32x4){0.f, 0.f, 0.f, 0.f};

    // prologue: 3 tiles in flight (12 vmem ops/thread)
    STAGE(0, 0);
    STAGE(1, 32);
    STAGE(2, 64);

    int axor = (hi ^ (l15 & 3)) * 8;    // read-side swizzle (row&3 == l15&3 for all frags)

#pragma unroll
    for (int t = 0; t < 16; ++t) {
        if (t < 14)       asm volatile("s_waitcnt vmcnt(8)" ::: "memory");
        else if (t == 14) asm volatile("s_waitcnt vmcnt(4)" ::: "memory");
        else              asm volatile("s_waitcnt vmcnt(0)" ::: "memory");
        __builtin_amdgcn_s_barrier();   // tile t landed everywhere
        const int bi = t & 3;
        short8 af[8], bfr[4];
#pragma unroll
        for (int rt = 0; rt < 8; ++rt)
            af[rt] = *(const short8*)(&aL[bi][(wr * 128 + rt * 16 + l15) * 32 + axor]);
#pragma unroll
        for (int ct = 0; ct < 4; ++ct)
            bfr[ct] = *(const short8*)(&bL[bi][(wc * 64 + ct * 16 + l15) * 32 + axor]);
        __builtin_amdgcn_s_setprio(1);
#pragma unroll
        for (int rt = 0; rt < 8; ++rt)
#pragma unroll
            for (int ct = 0; ct < 4; ++ct)
                acc[rt][ct] = __builtin_amdgcn_mfma_f32_16x16x32_bf16(af[rt], bfr[ct], acc[rt][ct], 0, 0, 0);
        __builtin_amdgcn_s_setprio(0);
        __builtin_amdgcn_s_barrier();   // all reads of tile t done everywhere
        if (t < 13) { STAGE((t + 3) & 3, (t + 3) * 32); }
    }
#undef STAGE

    // ---------------- epilogue: dot -> distance -> exp-sum + argmin ----------------
    float* red_s = (float*)aL;                         // [256][4] partial sums
    unsigned long long* red_m = (unsigned long long*)bL; // [256][4] packed argmin
    float cbn[4];
#pragma unroll
    for (int ct = 0; ct < 4; ++ct)
        cbn[ct] = cbnorm[col0 + wc * 64 + ct * 16 + l15];
#pragma unroll
    for (int rt = 0; rt < 8; ++rt) {
#pragma unroll
        for (int r = 0; r < 4; ++r) {
            int lrow = wr * 128 + rt * 16 + hi * 4 + r;  // 0..255 within tile
            int row = row0 + lrow;
            float xn = xnorm[row];
            float dt = sqrtf(dtg2[row]);
            float sv = 0.f, dm = 3.4e38f;
            unsigned ix = 0u;
#pragma unroll
            for (int ct = 0; ct < 4; ++ct) {
                float dot = acc[rt][ct][r];
                float d2 = fmaxf(xn + cbn[ct] - 2.f * dot, 0.f);
                float d = sqrtf(d2);
                sv += __expf(fminf(dt - d, 80.f));
                unsigned col = (unsigned)(col0 + wc * 64 + ct * 16 + l15);
                if (d < dm) { dm = d; ix = col; }
            }
#pragma unroll
            for (int m = 1; m < 16; m <<= 1) {
                sv += __shfl_xor(sv, m);
                float od = __shfl_xor(dm, m);
                unsigned oi = __shfl_xor(ix, m);
                if (od < dm || (od == dm && oi < ix)) { dm = od; ix = oi; }
            }
            if (l15 == 0) {
                red_s[lrow * 4 + wc] = sv;
                red_m[lrow * 4 + wc] = ((unsigned long long)__float_as_uint(dm) << 32)
                                     | (unsigned long long)ix;
            }
        }
    }
    __syncthreads();
    if (tid < 256) {
        float sv = red_s[tid * 4 + 0] + red_s[tid * 4 + 1]
                 + red_s[tid * 4 + 2] + red_s[tid * 4 + 3];
        unsigned long long pk = red_m[tid * 4 + 0];
        unsigned long long p1 = red_m[tid * 4 + 1]; if (p1 < pk) pk = p1;
        unsigned long long p2 = red_m[tid * 4 + 2]; if (p2 < pk) pk = p2;
        unsigned long long p3 = red_m[tid * 4 + 3]; if (p3 < pk) pk = p3;
        atomicAdd(&s_sum[row0 + tid], sv);
        atomicMin(&minpack[row0 + tid], pk);
    }
}

// ---------------- Kernel 3a: per-token CE/accuracy/emb-loss/target-dist reduce ----------------
__global__ __launch_bounds__(256) void k3a(
    const float* __restrict__ s_sum,
    const unsigned long long* __restrict__ minpack,
    const int* __restrict__ codes,
    const float* __restrict__ dtg2,
    float* __restrict__ accum)
{
    __shared__ float w0[4], w1[4], w2[4], w3[4];
    int tid = threadIdx.x;
    int n = blockIdx.x * 256 + tid;
    // s_sum[n] = sum_j exp(d_t - d_j)  =>  log(s_sum) = d_t + lse(-d) = per-token CE
    float ce = logf(s_sum[n]);
    unsigned pred = (unsigned)(minpack[n] & 0xFFFFFFFFull);
    float ok = (pred == (unsigned)codes[n]) ? 1.f : 0.f;
    float sq = dtg2[n];
    float td = sqrtf(sq);
#pragma unroll
    for (int m = 1; m < 64; m <<= 1) {
        ce += __shfl_xor(ce, m);
        ok += __shfl_xor(ok, m);
        sq += __shfl_xor(sq, m);
        td += __shfl_xor(td, m);
    }
    int lane = tid & 63, w = tid >> 6;
    if (lane == 0) { w0[w] = ce; w1[w] = ok; w2[w] = sq; w3[w] = td; }
    __syncthreads();
    if (tid == 0) {
        atomicAdd(&accum[0], w0[0] + w0[1] + w0[2] + w0[3]);
        atomicAdd(&accum[1], w1[0] + w1[1] + w1[2] + w1[3]);
        atomicAdd(&accum[2], w2[0] + w2[1] + w2[2] + w2[3]);
        atomicAdd(&accum[3], w3[0] + w3[1] + w3[2] + w3[3]);
    }
}

// ---------------- Kernel 3b: finalize 5 outputs ----------------
__global__ void k3b(const float* __restrict__ accum, float* __restrict__ out)
{
    if (threadIdx.x == 0 && blockIdx.x == 0) {
        float ce   = accum[0] / (float)N_TOK;
        float accy = accum[1] / (float)N_TOK;
        float emb  = accum[2] / ((float)N_TOK * (float)C_);
        float td   = accum[3] / (float)N_TOK;
        out[0] = emb + ce;   // total_loss (EMB_W=CE_W=1)
        out[1] = emb;        // emb_to_codebook_loss
        out[2] = ce;         // ce_loss
        out[3] = accy;       // token_accuracy
        out[4] = td;         // emb_to_target_dist
    }
}

extern "C" void kernel_launch(void* const* d_in, const int* in_sizes, int n_in,
                              void* d_out, int out_size, void* d_ws, size_t ws_size,
                              hipStream_t stream)
{
    const float* student  = (const float*)d_in[0];
    const int*   codes    = (const int*)d_in[1];
    const float* codebook = (const float*)d_in[2];
    // d_in[3] distance_matrix is unused by the reference.
    float* out = (float*)d_out;

    char* ws = (char*)d_ws;
    unsigned short* Abf   = (unsigned short*)(ws);                 // 16 MiB
    unsigned short* CBbf  = (unsigned short*)(ws + 16777216);      // 4 MiB
    float* xnorm          = (float*)(ws + 20971520);               // 64 KiB
    float* dtg2           = (float*)(ws + 21037056);               // 64 KiB
    float* cbnorm         = (float*)(ws + 21102592);               // 16 KiB
    float* s_sum          = (float*)(ws + 21118976);               // 64 KiB
    unsigned long long* minpack = (unsigned long long*)(ws + 21184512); // 128 KiB
    float* accum          = (float*)(ws + 21315584);               // 64 B

    // k1_cb zero-inits s_sum/minpack/xnorm/dtg2/accum (stream-ordered before k1_prep's atomics)
    hipLaunchKernelGGL(k1_cb, dim3(1024), dim3(256), 0, stream,
                       codebook, CBbf, cbnorm, s_sum, minpack, xnorm, dtg2, accum);
    hipLaunchKernelGGL(k1_prep, dim3(512), dim3(256), 0, stream,
                       student, codes, codebook, Abf, xnorm, dtg2);
    hipLaunchKernelGGL(k2_main, dim3(1024), dim3(512), 0, stream,
                       Abf, CBbf, xnorm, dtg2, cbnorm, s_sum, minpack);
    hipLaunchKernelGGL(k3a, dim3(64), dim3(256), 0, stream,
                       s_sum, minpack, codes, dtg2, accum);
    hipLaunchKernelGGL(k3b, dim3(1), dim3(64), 0, stream, accum, out);
}